// Round 8
// baseline (79.792 us; speedup 1.0000x reference)
//
#include <hip/hip_runtime.h>

#define D 128
#define CAP 96

// ---------------- fallback (round-1) kernel ----------------
__global__ __launch_bounds__(256) void transe_time_kernel(
    const int* __restrict__ idx, const float* __restrict__ ent,
    const float* __restrict__ rel, const float* __restrict__ tt,
    float* __restrict__ out, int B)
{
    const int b = blockIdx.x;
    if (b >= B) return;
    const int tid = threadIdx.x;
    const int e4  = tid & 31;
    const int g   = tid >> 5;

    __shared__ float sh_h[D];
    __shared__ float sh_t[D];
    __shared__ float ph[8][D];
    __shared__ float pt[8][D];
    __shared__ float wred[8];

    const int hi = idx[b * 5 + 0];
    const int ri = idx[b * 5 + 1];
    const int ti = idx[b * 5 + 2];
    const int si = idx[b * 5 + 3];
    const int ei = idx[b * 5 + 4];

    if (tid < D) {
        sh_h[tid] = ent[(size_t)hi * D + tid];
        sh_t[tid] = ent[(size_t)ti * D + tid];
    }
    __syncthreads();

    const float4* __restrict__ Ts = (const float4*)(tt + (size_t)si * D * D);
    const float4* __restrict__ Te = (const float4*)(tt + (size_t)ei * D * D);

    float4 hacc = make_float4(0.f, 0.f, 0.f, 0.f);
    float4 tacc = make_float4(0.f, 0.f, 0.f, 0.f);

    #pragma unroll 4
    for (int d0 = 0; d0 < D; d0 += 8) {
        const int d = d0 + g;
        const float4 a = Ts[d * 32 + e4];
        const float4 c = Te[d * 32 + e4];
        const float hd = sh_h[d];
        const float td = sh_t[d];
        const float mx = a.x + c.x;
        const float my = a.y + c.y;
        const float mz = a.z + c.z;
        const float mw = a.w + c.w;
        hacc.x += hd * mx; hacc.y += hd * my; hacc.z += hd * mz; hacc.w += hd * mw;
        tacc.x += td * mx; tacc.y += td * my; tacc.z += td * mz; tacc.w += td * mw;
    }

    ((float4*)ph[g])[e4] = hacc;
    ((float4*)pt[g])[e4] = tacc;
    __syncthreads();

    float h2 = 0.f, t2 = 0.f;
    if (tid < D) {
        #pragma unroll
        for (int k = 0; k < 8; ++k) { h2 += ph[k][tid]; t2 += pt[k][tid]; }
    }
    float nh = h2 * h2;
    float nt = t2 * t2;
    #pragma unroll
    for (int off = 32; off; off >>= 1) {
        nh += __shfl_down(nh, off, 64);
        nt += __shfl_down(nt, off, 64);
    }
    const int wv = tid >> 6;
    if ((tid & 63) == 0) { wred[wv * 2] = nh; wred[wv * 2 + 1] = nt; }
    __syncthreads();
    const float NH = wred[0] + wred[2] + wred[4] + wred[6];
    const float NT2 = wred[1] + wred[3] + wred[5] + wred[7];
    const float rnh = 1.0f / fmaxf(sqrtf(NH), 1e-12f);
    const float rnt = 1.0f / fmaxf(sqrtf(NT2), 1e-12f);

    float v = 0.f;
    if (tid < D) {
        const float rr = rel[(size_t)ri * D + tid];
        v = fabsf(h2 * rnh + rr - t2 * rnt + 1e-6f);
    }
    #pragma unroll
    for (int off = 32; off; off >>= 1) v += __shfl_down(v, off, 64);
    __syncthreads();
    if ((tid & 63) == 0) wred[wv] = v;
    __syncthreads();
    if (tid == 0) out[b] = wred[0] + wred[1] + wred[2] + wred[3];
}

// ---------------- binned pipeline: zero -> scatter -> matvec -> score -------

__global__ __launch_bounds__(1024) void zero_cnt_kernel(int* __restrict__ cnt, int NT)
{
    const int t = threadIdx.x;
    if (t < NT) cnt[t] = 0;
}

// fixed-capacity bins: entries[u*CAP + p] = b*2 + slot
__global__ __launch_bounds__(256) void scatter_kernel(
    const int* __restrict__ idx, int* __restrict__ cnt,
    int* __restrict__ entries, int B)
{
    const int i = blockIdx.x * blockDim.x + threadIdx.x;
    const int stride = gridDim.x * blockDim.x;
    for (int b = i; b < B; b += stride) {
        int u = idx[b * 5 + 3];
        int p = atomicAdd(&cnt[u], 1);
        if (p < CAP) entries[u * CAP + p] = b * 2 + 0;
        u = idx[b * 5 + 4];
        p = atomicAdd(&cnt[u], 1);
        if (p < CAP) entries[u * CAP + p] = b * 2 + 1;
    }
}

__device__ __forceinline__ void fma4(float4& a, float s, const float4& v) {
    a.x += s * v.x; a.y += s * v.y; a.z += s * v.z; a.w += s * v.w;
}

// block (u, half): bin u, output cols half*64..half*64+63. Per chunk: stage
// 32 gathered entity rows (full 128 floats) in LDS, then each thread computes
// 2 rows x 4 cols. 2000 blocks -> ~8/CU co-resident for latency hiding.
__global__ __launch_bounds__(256) void matvec_kernel(
    const int* __restrict__ idx, const float* __restrict__ ent,
    const float* __restrict__ tt, const int* __restrict__ cnt,
    const int* __restrict__ entries, float* __restrict__ P)
{
    const int u = blockIdx.x;
    const int half = blockIdx.y;
    int n = cnt[u];
    if (n == 0) return;
    if (n > CAP) n = CAP;
    const int rows = 2 * n;                // row 2j = h of entry j, 2j+1 = t
    const int base = u * CAP;
    const int tid = threadIdx.x;

    const int cg16 = tid & 15;             // col group 0..15
    const int rh   = tid >> 4;             // 0..15 -> rows rh, rh+16
    const int col0 = half * 64 + cg16 * 4;

    __shared__ float Esh[32][D + 4];       // +4 pad: E-row reads bank-spread
    const float* __restrict__ T = tt + (size_t)u * (D * D);
    const float* __restrict__ Tc = T + col0;

    for (int rr0 = 0; rr0 < rows; rr0 += 32) {
        {   // stage up to 32 full entity rows: 4x float4 per thread
            const int r  = tid >> 3;       // 0..31
            const int j8 = tid & 7;        // 0..7 -> floats j8*16 .. +15
            const int rr = rr0 + r;
            float4 v0 = make_float4(0.f, 0.f, 0.f, 0.f), v1 = v0, v2 = v0, v3 = v0;
            if (rr < rows) {
                const int e   = entries[base + (rr >> 1)];
                const int b   = e >> 1;
                const int eid = (rr & 1) ? idx[b * 5 + 2] : idx[b * 5 + 0];
                const float* src = ent + (size_t)eid * D + j8 * 16;
                v0 = *(const float4*)(src);
                v1 = *(const float4*)(src + 4);
                v2 = *(const float4*)(src + 8);
                v3 = *(const float4*)(src + 12);
            }
            *(float4*)&Esh[r][j8 * 16]      = v0;
            *(float4*)&Esh[r][j8 * 16 + 4]  = v1;
            *(float4*)&Esh[r][j8 * 16 + 8]  = v2;
            *(float4*)&Esh[r][j8 * 16 + 12] = v3;
        }
        __syncthreads();

        float4 acc0 = make_float4(0.f, 0.f, 0.f, 0.f);
        float4 acc1 = acc0;

        #pragma unroll 4
        for (int d4 = 0; d4 < D; d4 += 4) {
            const float* tp = Tc + (size_t)d4 * D;
            const float4 t0 = *(const float4*)(tp);
            const float4 t1 = *(const float4*)(tp + D);
            const float4 t2 = *(const float4*)(tp + 2 * D);
            const float4 t3 = *(const float4*)(tp + 3 * D);
            float4 e;
            e = *(const float4*)&Esh[rh][d4];
            fma4(acc0, e.x, t0); fma4(acc0, e.y, t1); fma4(acc0, e.z, t2); fma4(acc0, e.w, t3);
            e = *(const float4*)&Esh[rh + 16][d4];
            fma4(acc1, e.x, t0); fma4(acc1, e.y, t1); fma4(acc1, e.z, t2); fma4(acc1, e.w, t3);
        }

        #pragma unroll
        for (int jr = 0; jr < 2; ++jr) {
            const float4& a = (jr == 0) ? acc0 : acc1;
            const int rr = rr0 + rh + 16 * jr;
            if (rr < rows) {
                const int e    = entries[base + (rr >> 1)];
                const int b    = e >> 1;
                const int slot = e & 1;
                const int ht   = rr & 1;
                float* dst = P + ((size_t)(b * 2 + ht) * 2 + slot) * D + col0;
                *(float4*)dst = a;
            }
        }
        __syncthreads();
    }
}

__global__ __launch_bounds__(256) void score_kernel(
    const int* __restrict__ idx, const float* __restrict__ rel,
    const float* __restrict__ P, float* __restrict__ out, int B)
{
    const int tid = threadIdx.x;
    const int b = blockIdx.x * 4 + (tid >> 6);
    const int l = tid & 63;
    if (b >= B) return;

    const int ri = idx[b * 5 + 1];
    const float* ph = P + (size_t)(b * 2 + 0) * 2 * D;
    const float* pt = P + (size_t)(b * 2 + 1) * 2 * D;

    const float h0 = ph[l]      + ph[D + l];
    const float h1 = ph[64 + l] + ph[D + 64 + l];
    const float t0 = pt[l]      + pt[D + l];
    const float t1 = pt[64 + l] + pt[D + 64 + l];

    float nh = h0 * h0 + h1 * h1;
    float nt = t0 * t0 + t1 * t1;
    #pragma unroll
    for (int off = 32; off; off >>= 1) {
        nh += __shfl_down(nh, off, 64);
        nt += __shfl_down(nt, off, 64);
    }
    nh = __shfl(nh, 0, 64);
    nt = __shfl(nt, 0, 64);
    const float rnh = 1.0f / fmaxf(sqrtf(nh), 1e-12f);
    const float rnt = 1.0f / fmaxf(sqrtf(nt), 1e-12f);
    const float r0 = rel[(size_t)ri * D + l];
    const float r1 = rel[(size_t)ri * D + 64 + l];
    float v = fabsf(h0 * rnh + r0 - t0 * rnt + 1e-6f)
            + fabsf(h1 * rnh + r1 - t1 * rnt + 1e-6f);
    #pragma unroll
    for (int off = 32; off; off >>= 1) v += __shfl_down(v, off, 64);
    if (l == 0) out[b] = v;
}

extern "C" void kernel_launch(void* const* d_in, const int* in_sizes, int n_in,
                              void* d_out, int out_size, void* d_ws, size_t ws_size,
                              hipStream_t stream) {
    const int*   idx = (const int*)d_in[0];
    const float* ent = (const float*)d_in[1];
    const float* rel = (const float*)d_in[2];
    const float* tt  = (const float*)d_in[3];
    float* out = (float*)d_out;
    const int B  = in_sizes[0] / 5;
    const int NT = in_sizes[3] / (D * D);   // number of time matrices (1000)

    const size_t CNT_OFF = 0;
    const size_t ENT_OFF = 8192;
    const size_t ENT_BYTES = (size_t)NT * CAP * sizeof(int);
    const size_t P_OFF  = (ENT_OFF + ENT_BYTES + 255) & ~(size_t)255;
    const size_t need   = P_OFF + (size_t)B * 2 * 2 * D * sizeof(float);

    if (ws_size < need || NT > 1024) {
        transe_time_kernel<<<dim3(B), dim3(256), 0, stream>>>(idx, ent, rel, tt, out, B);
        return;
    }

    char* ws = (char*)d_ws;
    int* cnt     = (int*)(ws + CNT_OFF);
    int* entries = (int*)(ws + ENT_OFF);
    float* P     = (float*)(ws + P_OFF);

    zero_cnt_kernel<<<dim3(1),           dim3(1024), 0, stream>>>(cnt, NT);
    scatter_kernel <<<dim3(32),          dim3(256),  0, stream>>>(idx, cnt, entries, B);
    matvec_kernel  <<<dim3(NT, 2),       dim3(256),  0, stream>>>(idx, ent, tt, cnt, entries, P);
    score_kernel   <<<dim3((B + 3) / 4), dim3(256),  0, stream>>>(idx, rel, P, out, B);
}

// Round 9
// 53.403 us; speedup vs baseline: 1.4941x; 1.4941x over previous
//
#include <hip/hip_runtime.h>

#define D 128
#define CAP_R 128   // max staged rows per bin (rows = 2*entries; mean 32.8)

// ---------------- fallback (round-1) kernel ----------------
__global__ __launch_bounds__(256) void transe_time_kernel(
    const int* __restrict__ idx, const float* __restrict__ ent,
    const float* __restrict__ rel, const float* __restrict__ tt,
    float* __restrict__ out, int B)
{
    const int b = blockIdx.x;
    if (b >= B) return;
    const int tid = threadIdx.x;
    const int e4  = tid & 31;
    const int g   = tid >> 5;

    __shared__ float sh_h[D];
    __shared__ float sh_t[D];
    __shared__ float ph[8][D];
    __shared__ float pt[8][D];
    __shared__ float wred[8];

    const int hi = idx[b * 5 + 0];
    const int ri = idx[b * 5 + 1];
    const int ti = idx[b * 5 + 2];
    const int si = idx[b * 5 + 3];
    const int ei = idx[b * 5 + 4];

    if (tid < D) {
        sh_h[tid] = ent[(size_t)hi * D + tid];
        sh_t[tid] = ent[(size_t)ti * D + tid];
    }
    __syncthreads();

    const float4* __restrict__ Ts = (const float4*)(tt + (size_t)si * D * D);
    const float4* __restrict__ Te = (const float4*)(tt + (size_t)ei * D * D);

    float4 hacc = make_float4(0.f, 0.f, 0.f, 0.f);
    float4 tacc = make_float4(0.f, 0.f, 0.f, 0.f);

    #pragma unroll 4
    for (int d0 = 0; d0 < D; d0 += 8) {
        const int d = d0 + g;
        const float4 a = Ts[d * 32 + e4];
        const float4 c = Te[d * 32 + e4];
        const float hd = sh_h[d];
        const float td = sh_t[d];
        const float mx = a.x + c.x;
        const float my = a.y + c.y;
        const float mz = a.z + c.z;
        const float mw = a.w + c.w;
        hacc.x += hd * mx; hacc.y += hd * my; hacc.z += hd * mz; hacc.w += hd * mw;
        tacc.x += td * mx; tacc.y += td * my; tacc.z += td * mz; tacc.w += td * mw;
    }

    ((float4*)ph[g])[e4] = hacc;
    ((float4*)pt[g])[e4] = tacc;
    __syncthreads();

    float h2 = 0.f, t2 = 0.f;
    if (tid < D) {
        #pragma unroll
        for (int k = 0; k < 8; ++k) { h2 += ph[k][tid]; t2 += pt[k][tid]; }
    }
    float nh = h2 * h2;
    float nt = t2 * t2;
    #pragma unroll
    for (int off = 32; off; off >>= 1) {
        nh += __shfl_down(nh, off, 64);
        nt += __shfl_down(nt, off, 64);
    }
    const int wv = tid >> 6;
    if ((tid & 63) == 0) { wred[wv * 2] = nh; wred[wv * 2 + 1] = nt; }
    __syncthreads();
    const float NH = wred[0] + wred[2] + wred[4] + wred[6];
    const float NT2 = wred[1] + wred[3] + wred[5] + wred[7];
    const float rnh = 1.0f / fmaxf(sqrtf(NH), 1e-12f);
    const float rnt = 1.0f / fmaxf(sqrtf(NT2), 1e-12f);

    float v = 0.f;
    if (tid < D) {
        const float rr = rel[(size_t)ri * D + tid];
        v = fabsf(h2 * rnh + rr - t2 * rnt + 1e-6f);
    }
    #pragma unroll
    for (int off = 32; off; off >>= 1) v += __shfl_down(v, off, 64);
    __syncthreads();
    if ((tid & 63) == 0) wred[wv] = v;
    __syncthreads();
    if (tid == 0) out[b] = wred[0] + wred[1] + wred[2] + wred[3];
}

// ---------------- binned pipeline: zero -> scatter -> matvec -> score -------

__global__ __launch_bounds__(1024) void zero_cnt_kernel(int* __restrict__ cnt, int NT)
{
    const int t = threadIdx.x;
    if (t < NT) cnt[t] = 0;
}

// emits self-contained row records: rows[u*CAP_R + p] = {eid, dest}
// dest = (b*2 + ht)*2 + slot ; row pair (h,t) appended together.
__global__ __launch_bounds__(256) void scatter_kernel(
    const int* __restrict__ idx, int* __restrict__ cnt,
    int2* __restrict__ rowsbuf, int B)
{
    const int i = blockIdx.x * blockDim.x + threadIdx.x;
    const int stride = gridDim.x * blockDim.x;
    for (int b = i; b < B; b += stride) {
        const int h_eid = idx[b * 5 + 0];
        const int t_eid = idx[b * 5 + 2];
        #pragma unroll
        for (int slot = 0; slot < 2; ++slot) {
            const int u = idx[b * 5 + 3 + slot];
            const int p = atomicAdd(&cnt[u], 2);
            if (p + 1 < CAP_R) {
                rowsbuf[u * CAP_R + p]     = make_int2(h_eid, (b * 2 + 0) * 2 + slot);
                rowsbuf[u * CAP_R + p + 1] = make_int2(t_eid, (b * 2 + 1) * 2 + slot);
            }
        }
    }
}

__device__ __forceinline__ void fma4(float4& a, float s, const float4& v) {
    a.x += s * v.x; a.y += s * v.y; a.z += s * v.z; a.w += s * v.w;
}

// block u owns bin u. CHUNK=64 rows (covers ~all bins in ONE pass).
// Wave w computes cols w*32..w*32+31; each thread 8 rows x 4 cols.
// T streamed once per block (64KB, disjoint 16KB per wave).
__global__ __launch_bounds__(256) void matvec_kernel(
    const float* __restrict__ ent, const float* __restrict__ tt,
    const int* __restrict__ cnt, const int2* __restrict__ rowsbuf,
    float* __restrict__ P)
{
    const int u = blockIdx.x;
    int n_rows = cnt[u];
    if (n_rows == 0) return;
    if (n_rows > CAP_R) n_rows = CAP_R;
    const int base = u * CAP_R;
    const int tid = threadIdx.x;

    const int w    = tid >> 6;             // wave 0..3
    const int lane = tid & 63;
    const int c8   = lane & 7;             // 8 col-groups per wave
    const int rh   = lane >> 3;            // 0..7
    const int col0 = w * 32 + c8 * 4;

    __shared__ float Esh[64][D + 4];       // 33.8 KB
    __shared__ int   Dsh[64];
    const float* __restrict__ T = tt + (size_t)u * (D * D);

    for (int rr0 = 0; rr0 < n_rows; rr0 += 64) {
        {   // stage: thread handles row r = tid>>2, quarter q = tid&3 (32 floats)
            const int r  = tid >> 2;
            const int q  = tid & 3;
            const int rr = rr0 + r;
            if (rr < n_rows) {
                const int2 rec = rowsbuf[base + rr];
                const float* src = ent + (size_t)rec.x * D + q * 32;
                float4 v0 = *(const float4*)(src);
                float4 v1 = *(const float4*)(src + 4);
                float4 v2 = *(const float4*)(src + 8);
                float4 v3 = *(const float4*)(src + 12);
                float4 v4 = *(const float4*)(src + 16);
                float4 v5 = *(const float4*)(src + 20);
                float4 v6 = *(const float4*)(src + 24);
                float4 v7 = *(const float4*)(src + 28);
                float* drow = &Esh[r][q * 32];
                *(float4*)(drow)      = v0;
                *(float4*)(drow + 4)  = v1;
                *(float4*)(drow + 8)  = v2;
                *(float4*)(drow + 12) = v3;
                *(float4*)(drow + 16) = v4;
                *(float4*)(drow + 20) = v5;
                *(float4*)(drow + 24) = v6;
                *(float4*)(drow + 28) = v7;
                if (q == 0) Dsh[r] = rec.y;
            }
        }
        __syncthreads();

        float4 acc0 = make_float4(0.f, 0.f, 0.f, 0.f);
        float4 acc1 = acc0, acc2 = acc0, acc3 = acc0;
        float4 acc4 = acc0, acc5 = acc0, acc6 = acc0, acc7 = acc0;

        const float* Tc = T + col0;
        #pragma unroll 2
        for (int d4 = 0; d4 < D; d4 += 4) {
            const float* tp = Tc + (size_t)d4 * D;
            const float4 t0 = *(const float4*)(tp);
            const float4 t1 = *(const float4*)(tp + D);
            const float4 t2 = *(const float4*)(tp + 2 * D);
            const float4 t3 = *(const float4*)(tp + 3 * D);
            float4 e;
            e = *(const float4*)&Esh[rh][d4];
            fma4(acc0, e.x, t0); fma4(acc0, e.y, t1); fma4(acc0, e.z, t2); fma4(acc0, e.w, t3);
            e = *(const float4*)&Esh[rh + 8][d4];
            fma4(acc1, e.x, t0); fma4(acc1, e.y, t1); fma4(acc1, e.z, t2); fma4(acc1, e.w, t3);
            e = *(const float4*)&Esh[rh + 16][d4];
            fma4(acc2, e.x, t0); fma4(acc2, e.y, t1); fma4(acc2, e.z, t2); fma4(acc2, e.w, t3);
            e = *(const float4*)&Esh[rh + 24][d4];
            fma4(acc3, e.x, t0); fma4(acc3, e.y, t1); fma4(acc3, e.z, t2); fma4(acc3, e.w, t3);
            e = *(const float4*)&Esh[rh + 32][d4];
            fma4(acc4, e.x, t0); fma4(acc4, e.y, t1); fma4(acc4, e.z, t2); fma4(acc4, e.w, t3);
            e = *(const float4*)&Esh[rh + 40][d4];
            fma4(acc5, e.x, t0); fma4(acc5, e.y, t1); fma4(acc5, e.z, t2); fma4(acc5, e.w, t3);
            e = *(const float4*)&Esh[rh + 48][d4];
            fma4(acc6, e.x, t0); fma4(acc6, e.y, t1); fma4(acc6, e.z, t2); fma4(acc6, e.w, t3);
            e = *(const float4*)&Esh[rh + 56][d4];
            fma4(acc7, e.x, t0); fma4(acc7, e.y, t1); fma4(acc7, e.z, t2); fma4(acc7, e.w, t3);
        }

        #pragma unroll
        for (int k = 0; k < 8; ++k) {
            const float4& a = (k == 0) ? acc0 : (k == 1) ? acc1 : (k == 2) ? acc2 :
                              (k == 3) ? acc3 : (k == 4) ? acc4 : (k == 5) ? acc5 :
                              (k == 6) ? acc6 : acc7;
            const int r  = rh + 8 * k;
            const int rr = rr0 + r;
            if (rr < n_rows) {
                float* dst = P + (size_t)Dsh[r] * D + col0;
                *(float4*)dst = a;
            }
        }
        __syncthreads();
    }
}

__global__ __launch_bounds__(256) void score_kernel(
    const int* __restrict__ idx, const float* __restrict__ rel,
    const float* __restrict__ P, float* __restrict__ out, int B)
{
    const int tid = threadIdx.x;
    const int b = blockIdx.x * 4 + (tid >> 6);
    const int l = tid & 63;
    if (b >= B) return;

    const int ri = idx[b * 5 + 1];
    const float* ph = P + (size_t)(b * 2 + 0) * 2 * D;
    const float* pt = P + (size_t)(b * 2 + 1) * 2 * D;

    const float h0 = ph[l]      + ph[D + l];
    const float h1 = ph[64 + l] + ph[D + 64 + l];
    const float t0 = pt[l]      + pt[D + l];
    const float t1 = pt[64 + l] + pt[D + 64 + l];

    float nh = h0 * h0 + h1 * h1;
    float nt = t0 * t0 + t1 * t1;
    #pragma unroll
    for (int off = 32; off; off >>= 1) {
        nh += __shfl_down(nh, off, 64);
        nt += __shfl_down(nt, off, 64);
    }
    nh = __shfl(nh, 0, 64);
    nt = __shfl(nt, 0, 64);
    const float rnh = 1.0f / fmaxf(sqrtf(nh), 1e-12f);
    const float rnt = 1.0f / fmaxf(sqrtf(nt), 1e-12f);
    const float r0 = rel[(size_t)ri * D + l];
    const float r1 = rel[(size_t)ri * D + 64 + l];
    float v = fabsf(h0 * rnh + r0 - t0 * rnt + 1e-6f)
            + fabsf(h1 * rnh + r1 - t1 * rnt + 1e-6f);
    #pragma unroll
    for (int off = 32; off; off >>= 1) v += __shfl_down(v, off, 64);
    if (l == 0) out[b] = v;
}

extern "C" void kernel_launch(void* const* d_in, const int* in_sizes, int n_in,
                              void* d_out, int out_size, void* d_ws, size_t ws_size,
                              hipStream_t stream) {
    const int*   idx = (const int*)d_in[0];
    const float* ent = (const float*)d_in[1];
    const float* rel = (const float*)d_in[2];
    const float* tt  = (const float*)d_in[3];
    float* out = (float*)d_out;
    const int B  = in_sizes[0] / 5;
    const int NT = in_sizes[3] / (D * D);   // number of time matrices (1000)

    const size_t CNT_OFF  = 0;
    const size_t ROWS_OFF = 8192;
    const size_t ROWS_BYTES = (size_t)NT * CAP_R * sizeof(int2);
    const size_t P_OFF  = (ROWS_OFF + ROWS_BYTES + 255) & ~(size_t)255;
    const size_t need   = P_OFF + (size_t)B * 2 * 2 * D * sizeof(float);

    if (ws_size < need || NT > 1024) {
        transe_time_kernel<<<dim3(B), dim3(256), 0, stream>>>(idx, ent, rel, tt, out, B);
        return;
    }

    char* ws = (char*)d_ws;
    int*  cnt     = (int*)(ws + CNT_OFF);
    int2* rowsbuf = (int2*)(ws + ROWS_OFF);
    float* P      = (float*)(ws + P_OFF);

    zero_cnt_kernel<<<dim3(1),           dim3(1024), 0, stream>>>(cnt, NT);
    scatter_kernel <<<dim3(32),          dim3(256),  0, stream>>>(idx, cnt, rowsbuf, B);
    matvec_kernel  <<<dim3(NT),          dim3(256),  0, stream>>>(ent, tt, cnt, rowsbuf, P);
    score_kernel   <<<dim3((B + 3) / 4), dim3(256),  0, stream>>>(idx, rel, P, out, B);
}

// Round 10
// 51.491 us; speedup vs baseline: 1.5496x; 1.0371x over previous
//
#include <hip/hip_runtime.h>

#define D 128
#define CAP_R 128   // max staged rows per bin (rows = 2*entries; mean 32.8, sd ~8)

// ---------------- fallback (round-1) kernel ----------------
__global__ __launch_bounds__(256) void transe_time_kernel(
    const int* __restrict__ idx, const float* __restrict__ ent,
    const float* __restrict__ rel, const float* __restrict__ tt,
    float* __restrict__ out, int B)
{
    const int b = blockIdx.x;
    if (b >= B) return;
    const int tid = threadIdx.x;
    const int e4  = tid & 31;
    const int g   = tid >> 5;

    __shared__ float sh_h[D];
    __shared__ float sh_t[D];
    __shared__ float ph[8][D];
    __shared__ float pt[8][D];
    __shared__ float wred[8];

    const int hi = idx[b * 5 + 0];
    const int ri = idx[b * 5 + 1];
    const int ti = idx[b * 5 + 2];
    const int si = idx[b * 5 + 3];
    const int ei = idx[b * 5 + 4];

    if (tid < D) {
        sh_h[tid] = ent[(size_t)hi * D + tid];
        sh_t[tid] = ent[(size_t)ti * D + tid];
    }
    __syncthreads();

    const float4* __restrict__ Ts = (const float4*)(tt + (size_t)si * D * D);
    const float4* __restrict__ Te = (const float4*)(tt + (size_t)ei * D * D);

    float4 hacc = make_float4(0.f, 0.f, 0.f, 0.f);
    float4 tacc = make_float4(0.f, 0.f, 0.f, 0.f);

    #pragma unroll 4
    for (int d0 = 0; d0 < D; d0 += 8) {
        const int d = d0 + g;
        const float4 a = Ts[d * 32 + e4];
        const float4 c = Te[d * 32 + e4];
        const float hd = sh_h[d];
        const float td = sh_t[d];
        const float mx = a.x + c.x;
        const float my = a.y + c.y;
        const float mz = a.z + c.z;
        const float mw = a.w + c.w;
        hacc.x += hd * mx; hacc.y += hd * my; hacc.z += hd * mz; hacc.w += hd * mw;
        tacc.x += td * mx; tacc.y += td * my; tacc.z += td * mz; tacc.w += td * mw;
    }

    ((float4*)ph[g])[e4] = hacc;
    ((float4*)pt[g])[e4] = tacc;
    __syncthreads();

    float h2 = 0.f, t2 = 0.f;
    if (tid < D) {
        #pragma unroll
        for (int k = 0; k < 8; ++k) { h2 += ph[k][tid]; t2 += pt[k][tid]; }
    }
    float nh = h2 * h2;
    float nt = t2 * t2;
    #pragma unroll
    for (int off = 32; off; off >>= 1) {
        nh += __shfl_down(nh, off, 64);
        nt += __shfl_down(nt, off, 64);
    }
    const int wv = tid >> 6;
    if ((tid & 63) == 0) { wred[wv * 2] = nh; wred[wv * 2 + 1] = nt; }
    __syncthreads();
    const float NH = wred[0] + wred[2] + wred[4] + wred[6];
    const float NT2 = wred[1] + wred[3] + wred[5] + wred[7];
    const float rnh = 1.0f / fmaxf(sqrtf(NH), 1e-12f);
    const float rnt = 1.0f / fmaxf(sqrtf(NT2), 1e-12f);

    float v = 0.f;
    if (tid < D) {
        const float rr = rel[(size_t)ri * D + tid];
        v = fabsf(h2 * rnh + rr - t2 * rnt + 1e-6f);
    }
    #pragma unroll
    for (int off = 32; off; off >>= 1) v += __shfl_down(v, off, 64);
    __syncthreads();
    if ((tid & 63) == 0) wred[wv] = v;
    __syncthreads();
    if (tid == 0) out[b] = wred[0] + wred[1] + wred[2] + wred[3];
}

// ---------------- binned pipeline: zero -> scatter -> matvec -> score -------

__global__ __launch_bounds__(1024) void zero_cnt_kernel(int* __restrict__ cnt, int NT)
{
    const int t = threadIdx.x;
    if (t < NT) cnt[t] = 0;
}

// emits self-contained row records: rows[u*CAP_R + p] = {eid, dest}
// dest = (b*2 + ht)*2 + slot ; row pair (h,t) appended together.
__global__ __launch_bounds__(256) void scatter_kernel(
    const int* __restrict__ idx, int* __restrict__ cnt,
    int2* __restrict__ rowsbuf, int B)
{
    const int i = blockIdx.x * blockDim.x + threadIdx.x;
    const int stride = gridDim.x * blockDim.x;
    for (int b = i; b < B; b += stride) {
        const int h_eid = idx[b * 5 + 0];
        const int t_eid = idx[b * 5 + 2];
        #pragma unroll
        for (int slot = 0; slot < 2; ++slot) {
            const int u = idx[b * 5 + 3 + slot];
            const int p = atomicAdd(&cnt[u], 2);
            if (p + 1 < CAP_R) {
                rowsbuf[u * CAP_R + p]     = make_int2(h_eid, (b * 2 + 0) * 2 + slot);
                rowsbuf[u * CAP_R + p + 1] = make_int2(t_eid, (b * 2 + 1) * 2 + slot);
            }
        }
    }
}

__device__ __forceinline__ void fma4(float4& a, float s, const float4& v) {
    a.x += s * v.x; a.y += s * v.y; a.z += s * v.z; a.w += s * v.w;
}

// NG = number of live 8-row groups (wave-uniform). Computes NG row-groups x
// 4 cols per thread over the full d=128 contraction, then stores live rows.
template<int NG>
__device__ __forceinline__ void compute_store(
    const float* __restrict__ Tc, const float (*__restrict__ Esh)[D + 4],
    const int* __restrict__ Dsh, float* __restrict__ P,
    const int col0, const int rh, const int my_rows)
{
    float4 acc[NG];
    #pragma unroll
    for (int k = 0; k < NG; ++k) acc[k] = make_float4(0.f, 0.f, 0.f, 0.f);

    #pragma unroll 2
    for (int d4 = 0; d4 < D; d4 += 4) {
        const float* tp = Tc + (size_t)d4 * D;
        const float4 t0 = *(const float4*)(tp);
        const float4 t1 = *(const float4*)(tp + D);
        const float4 t2 = *(const float4*)(tp + 2 * D);
        const float4 t3 = *(const float4*)(tp + 3 * D);
        #pragma unroll
        for (int k = 0; k < NG; ++k) {
            const float4 e = *(const float4*)&Esh[rh + 8 * k][d4];
            fma4(acc[k], e.x, t0); fma4(acc[k], e.y, t1);
            fma4(acc[k], e.z, t2); fma4(acc[k], e.w, t3);
        }
    }

    #pragma unroll
    for (int k = 0; k < NG; ++k) {
        const int r = rh + 8 * k;
        if (r < my_rows) {
            float* dst = P + (size_t)Dsh[r] * D + col0;
            *(float4*)dst = acc[k];
        }
    }
}

// block (u, half): rows [half*32, half*32+32) of bin u (disjoint staging).
// Linear block id = u + half*NT; NT % 8 == 0 -> both halves on same XCD, so
// the second T-stream hits that XCD's L2. 17KB LDS -> 8 blocks/CU.
__global__ __launch_bounds__(256) void matvec_kernel(
    const float* __restrict__ ent, const float* __restrict__ tt,
    const int* __restrict__ cnt, const int2* __restrict__ rowsbuf,
    float* __restrict__ P)
{
    const int u = blockIdx.x;
    int n_rows = cnt[u];
    if (n_rows > CAP_R) n_rows = CAP_R;
    const int base = u * CAP_R;
    const int tid = threadIdx.x;

    const int w    = tid >> 6;             // wave 0..3 -> col slice w*32
    const int lane = tid & 63;
    const int c8   = lane & 7;             // col group within slice
    const int rh   = lane >> 3;            // 0..7
    const int col0 = w * 32 + c8 * 4;

    __shared__ float Esh[32][D + 4];       // 16.9 KB
    __shared__ int   Dsh[32];
    const float* __restrict__ T = tt + (size_t)u * (D * D);
    const float* __restrict__ Tc = T + col0;

    for (int rr0 = blockIdx.y * 32; rr0 < n_rows; rr0 += 64) {
        const int my_rows = min(32, n_rows - rr0);

        {   // stage my_rows entity rows: 8 threads/row, 16 floats each
            const int r  = tid >> 3;       // 0..31
            const int j8 = tid & 7;        // floats j8*16 .. +15
            if (r < my_rows) {
                const int2 rec = rowsbuf[base + rr0 + r];
                const float* src = ent + (size_t)rec.x * D + j8 * 16;
                const float4 v0 = *(const float4*)(src);
                const float4 v1 = *(const float4*)(src + 4);
                const float4 v2 = *(const float4*)(src + 8);
                const float4 v3 = *(const float4*)(src + 12);
                float* drow = &Esh[r][j8 * 16];
                *(float4*)(drow)      = v0;
                *(float4*)(drow + 4)  = v1;
                *(float4*)(drow + 8)  = v2;
                *(float4*)(drow + 12) = v3;
                if (j8 == 0) Dsh[r] = rec.y;
            }
        }
        __syncthreads();

        const int ng = (my_rows + 7) >> 3;   // 1..4, wave-uniform
        switch (ng) {
            case 1: compute_store<1>(Tc, Esh, Dsh, P, col0, rh, my_rows); break;
            case 2: compute_store<2>(Tc, Esh, Dsh, P, col0, rh, my_rows); break;
            case 3: compute_store<3>(Tc, Esh, Dsh, P, col0, rh, my_rows); break;
            default: compute_store<4>(Tc, Esh, Dsh, P, col0, rh, my_rows); break;
        }
        __syncthreads();
    }
}

__global__ __launch_bounds__(256) void score_kernel(
    const int* __restrict__ idx, const float* __restrict__ rel,
    const float* __restrict__ P, float* __restrict__ out, int B)
{
    const int tid = threadIdx.x;
    const int b = blockIdx.x * 4 + (tid >> 6);
    const int l = tid & 63;
    if (b >= B) return;

    const int ri = idx[b * 5 + 1];
    const float* ph = P + (size_t)(b * 2 + 0) * 2 * D;
    const float* pt = P + (size_t)(b * 2 + 1) * 2 * D;

    const float h0 = ph[l]      + ph[D + l];
    const float h1 = ph[64 + l] + ph[D + 64 + l];
    const float t0 = pt[l]      + pt[D + l];
    const float t1 = pt[64 + l] + pt[D + 64 + l];

    float nh = h0 * h0 + h1 * h1;
    float nt = t0 * t0 + t1 * t1;
    #pragma unroll
    for (int off = 32; off; off >>= 1) {
        nh += __shfl_down(nh, off, 64);
        nt += __shfl_down(nt, off, 64);
    }
    nh = __shfl(nh, 0, 64);
    nt = __shfl(nt, 0, 64);
    const float rnh = 1.0f / fmaxf(sqrtf(nh), 1e-12f);
    const float rnt = 1.0f / fmaxf(sqrtf(nt), 1e-12f);
    const float r0 = rel[(size_t)ri * D + l];
    const float r1 = rel[(size_t)ri * D + 64 + l];
    float v = fabsf(h0 * rnh + r0 - t0 * rnt + 1e-6f)
            + fabsf(h1 * rnh + r1 - t1 * rnt + 1e-6f);
    #pragma unroll
    for (int off = 32; off; off >>= 1) v += __shfl_down(v, off, 64);
    if (l == 0) out[b] = v;
}

extern "C" void kernel_launch(void* const* d_in, const int* in_sizes, int n_in,
                              void* d_out, int out_size, void* d_ws, size_t ws_size,
                              hipStream_t stream) {
    const int*   idx = (const int*)d_in[0];
    const float* ent = (const float*)d_in[1];
    const float* rel = (const float*)d_in[2];
    const float* tt  = (const float*)d_in[3];
    float* out = (float*)d_out;
    const int B  = in_sizes[0] / 5;
    const int NT = in_sizes[3] / (D * D);   // number of time matrices (1000)

    const size_t CNT_OFF  = 0;
    const size_t ROWS_OFF = 8192;
    const size_t ROWS_BYTES = (size_t)NT * CAP_R * sizeof(int2);
    const size_t P_OFF  = (ROWS_OFF + ROWS_BYTES + 255) & ~(size_t)255;
    const size_t need   = P_OFF + (size_t)B * 2 * 2 * D * sizeof(float);

    if (ws_size < need || NT > 1024) {
        transe_time_kernel<<<dim3(B), dim3(256), 0, stream>>>(idx, ent, rel, tt, out, B);
        return;
    }

    char* ws = (char*)d_ws;
    int*  cnt     = (int*)(ws + CNT_OFF);
    int2* rowsbuf = (int2*)(ws + ROWS_OFF);
    float* P      = (float*)(ws + P_OFF);

    zero_cnt_kernel<<<dim3(1),           dim3(1024), 0, stream>>>(cnt, NT);
    scatter_kernel <<<dim3(32),          dim3(256),  0, stream>>>(idx, cnt, rowsbuf, B);
    matvec_kernel  <<<dim3(NT, 2),       dim3(256),  0, stream>>>(ent, tt, cnt, rowsbuf, P);
    score_kernel   <<<dim3((B + 3) / 4), dim3(256),  0, stream>>>(idx, rel, P, out, B);
}